// Round 7
// baseline (327.838 us; speedup 1.0000x reference)
//
#include <hip/hip_runtime.h>
#include <hip/hip_bf16.h>

typedef __bf16 bf16x8 __attribute__((ext_vector_type(8)));
typedef float f32x4 __attribute__((ext_vector_type(4)));
typedef short s16x8 __attribute__((ext_vector_type(8)));

#define DEV __device__ __forceinline__

DEV float b2f(unsigned short u) {
  unsigned int x = ((unsigned int)u) << 16;
  return __builtin_bit_cast(float, x);
}
DEV unsigned short f2b(float f) {
  unsigned int x = __builtin_bit_cast(unsigned int, f);
  x += 0x7fffu + ((x >> 16) & 1u);
  return (unsigned short)(x >> 16);
}
DEV unsigned int f2b2(float a, float b) {
  float2 t; t.x = a; t.y = b;
  __hip_bfloat162 v = __float22bfloat162_rn(t);
  unsigned int r;
  __builtin_memcpy(&r, &v, 4);
  return r;
}
DEV f32x4 mfma16(bf16x8 a, bf16x8 b, f32x4 c) {
  return __builtin_amdgcn_mfma_f32_16x16x32_bf16(a, b, c, 0, 0, 0);
}
DEV void gl2lds16(const unsigned short* g, unsigned short* l) {
  __builtin_amdgcn_global_load_lds(
      (const __attribute__((address_space(1))) void*)g,
      (__attribute__((address_space(3))) void*)l, 16, 0, 0);
}

// ------- tiled transpose + f32->bf16 convert: in[K][N] f32 (+z) -> out[N][K] bf16 -------
__global__ __launch_bounds__(256)
void transpose_k(const float* __restrict__ in, unsigned short* __restrict__ out,
                 int K, int N, long zin, long zout) {
  __shared__ float tile[32][33];
  in  += (size_t)blockIdx.z * zin;
  out += (size_t)blockIdx.z * zout;
  int n0 = blockIdx.x * 32, k0 = blockIdx.y * 32;
  int tx = threadIdx.x, ty = threadIdx.y;
  #pragma unroll
  for (int i = ty; i < 32; i += 8)
    tile[i][tx] = in[(size_t)(k0 + i) * N + n0 + tx];
  __syncthreads();
  #pragma unroll
  for (int i = ty; i < 32; i += 8)
    out[(size_t)(n0 + i) * K + k0 + tx] = f2b(tile[tx][i]);
}

// ------- fused QKV weight transpose: wq/wk/wv [16][1024][64] f32 -> [3072][1024] bf16 ----
__global__ __launch_bounds__(256)
void transpose_qkv(const float* __restrict__ wq, const float* __restrict__ wk,
                   const float* __restrict__ wv, unsigned short* __restrict__ out) {
  __shared__ float tile[32][33];
  const int z = blockIdx.z;   // 0..47
  const float* in = (z < 16) ? (wq + (size_t)z * 65536)
                  : (z < 32) ? (wk + (size_t)(z - 16) * 65536)
                             : (wv + (size_t)(z - 32) * 65536);
  unsigned short* o = out + (size_t)z * 65536;
  int n0 = blockIdx.x * 32, k0 = blockIdx.y * 32;   // N=64, K=1024
  int tx = threadIdx.x, ty = threadIdx.y;
  #pragma unroll
  for (int i = ty; i < 32; i += 8)
    tile[i][tx] = in[(size_t)(k0 + i) * 64 + n0 + tx];
  __syncthreads();
  #pragma unroll
  for (int i = ty; i < 32; i += 8)
    o[(size_t)(n0 + i) * 1024 + k0 + tx] = f2b(tile[tx][i]);
}

// ---------------- LayerNorm over rows of 1024: f32 in -> bf16 out ----------------
__global__ __launch_bounds__(256)
void ln_kernel(const float* __restrict__ x, const float* __restrict__ g,
               const float* __restrict__ b, unsigned short* __restrict__ o) {
  __shared__ float rs[4];
  __shared__ float rq[4];
  int row = blockIdx.x, tid = threadIdx.x;
  const float* xr = x + (size_t)row * 1024;
  float4 raw = ((const float4*)xr)[tid];
  float s = raw.x + raw.y + raw.z + raw.w;
  float q = raw.x*raw.x + raw.y*raw.y + raw.z*raw.z + raw.w*raw.w;
  #pragma unroll
  for (int off = 32; off > 0; off >>= 1) {
    s += __shfl_down(s, off);
    q += __shfl_down(q, off);
  }
  int wave = tid >> 6;
  if ((tid & 63) == 0) { rs[wave] = s; rq[wave] = q; }
  __syncthreads();
  float ts = rs[0] + rs[1] + rs[2] + rs[3];
  float tq = rq[0] + rq[1] + rq[2] + rq[3];
  float mean = ts * (1.0f/1024.0f);
  float var = tq * (1.0f/1024.0f) - mean*mean;
  float rstd = rsqrtf(var + 1e-5f);
  float4 gr = ((const float4*)g)[tid];
  float4 br = ((const float4*)b)[tid];
  float o0 = (raw.x-mean)*rstd*gr.x + br.x;
  float o1 = (raw.y-mean)*rstd*gr.y + br.y;
  float o2 = (raw.z-mean)*rstd*gr.z + br.z;
  float o3 = (raw.w-mean)*rstd*gr.w + br.w;
  uint2 ov;
  ov.x = f2b2(o0, o1);
  ov.y = f2b2(o2, o3);
  ((uint2*)(o + (size_t)row * 1024))[tid] = ov;
}

// ======== GEMM 256x256, BK=32, 8 waves, 4-deep LDS ring, counted vmcnt + setprio ========
template<bool RELU, bool BIAS, bool VFUSE>
__global__ __launch_bounds__(512, 2)
void gemm8p(const unsigned short* __restrict__ A, const unsigned short* __restrict__ Bt,
            const float* __restrict__ bias, void* __restrict__ Cv,
            unsigned short* __restrict__ vT, int NTn, int N, int K) {
  __shared__ unsigned short As[4][256*32];   // 4 x 16 KB
  __shared__ unsigned short Bs[4][256*32];   // 4 x 16 KB  (128 KB total)
  const int tid = threadIdx.x;
  const int lane = tid & 63, wave = tid >> 6;
  const int quad = lane >> 4, l16 = lane & 15;
  const int wm = wave >> 2, wn = wave & 3;       // 2 x 4 wave grid
  const int nwg = gridDim.x;
  const int id = blockIdx.x;
  const int id2 = (id & 7) * (nwg >> 3) + (id >> 3);  // XCD-chunked (nwg % 8 == 0)
  const int mt = id2 / NTn, nt = id2 % NTn;
  const int m0 = mt * 256, n0 = nt * 256;

  f32x4 acc[8][4];
  #pragma unroll
  for (int i = 0; i < 8; ++i)
    #pragma unroll
    for (int j = 0; j < 4; ++j) acc[i][j] = (f32x4){0.f, 0.f, 0.f, 0.f};

  const int srow = tid >> 2;                               // 0..127
  const int scc  = (((tid & 3) ^ ((srow >> 1) & 3)) * 8);  // pre-swizzled source chunk
  const unsigned short* Ab = A + (size_t)m0 * K;
  const unsigned short* Bb = Bt + (size_t)n0 * K;

  const int NT = K >> 5;         // K-tiles (K=1024 -> 32)
  const int H  = NT << 2;        // half-tile stream length

  auto stage = [&](int h) {
    const int Tt = h >> 2, part = h & 3, kk = Tt << 5;
    const int buf = Tt & 3;
    if (part == 0)
      gl2lds16(Ab + (size_t)srow * K + kk + scc,         &As[buf][tid * 8]);
    else if (part == 1)
      gl2lds16(Ab + (size_t)(srow + 128) * K + kk + scc, &As[buf][4096 + tid * 8]);
    else if (part == 2)
      gl2lds16(Bb + (size_t)srow * K + kk + scc,         &Bs[buf][tid * 8]);
    else
      gl2lds16(Bb + (size_t)(srow + 128) * K + kk + scc, &Bs[buf][4096 + tid * 8]);
  };

  // prologue: tiles 0,1 fully + tile 2's A halves in flight
  #pragma unroll
  for (int h = 0; h < 10; ++h) stage(h);
  asm volatile("s_waitcnt vmcnt(6)" ::: "memory");   // tile 0 resident
  asm volatile("s_barrier" ::: "memory");

  const int qsw = (quad ^ ((l16 >> 1) & 3)) * 8;   // lane-constant read swizzle
  const int arow0 = wm * 128 + l16;
  const int brow0 = wn * 64 + l16;

  for (int T = 0; T < NT; ++T) {
    const int buf = T & 3;
    bf16x8 bq[4];
    // ---------- phase 1 (rows 0..63 of wave tile) ----------
    {
      bf16x8 af[4];
      #pragma unroll
      for (int i = 0; i < 4; ++i)
        af[i] = __builtin_bit_cast(bf16x8,
          *(const s16x8*)&As[buf][(arow0 + i*16)*32 + qsw]);
      #pragma unroll
      for (int j = 0; j < 4; ++j)
        bq[j] = __builtin_bit_cast(bf16x8,
          *(const s16x8*)&Bs[buf][(brow0 + j*16)*32 + qsw]);
      const int h = 4*T + 10;
      if (h < H)     stage(h);
      if (h + 1 < H) stage(h + 1);
      asm volatile("s_barrier" ::: "memory");
      __builtin_amdgcn_s_setprio(1);
      #pragma unroll
      for (int i = 0; i < 4; ++i)
        #pragma unroll
        for (int j = 0; j < 4; ++j)
          acc[i][j] = mfma16(af[i], bq[j], acc[i][j]);
      __builtin_amdgcn_s_setprio(0);
      asm volatile("s_barrier" ::: "memory");
    }
    // ---------- phase 2 (rows 64..127 of wave tile) ----------
    {
      bf16x8 af[4];
      #pragma unroll
      for (int i = 0; i < 4; ++i)
        af[i] = __builtin_bit_cast(bf16x8,
          *(const s16x8*)&As[buf][(arow0 + 64 + i*16)*32 + qsw]);
      const int h = 4*T + 12;
      if (h < H)     stage(h);
      if (h + 1 < H) stage(h + 1);
      if (T + 3 < NT)      { asm volatile("s_waitcnt vmcnt(6)" ::: "memory"); }
      else if (T + 2 < NT) { asm volatile("s_waitcnt vmcnt(4)" ::: "memory"); }
      else if (T + 1 < NT) { asm volatile("s_waitcnt vmcnt(0)" ::: "memory"); }
      asm volatile("s_barrier" ::: "memory");
      __builtin_amdgcn_s_setprio(1);
      #pragma unroll
      for (int i = 0; i < 4; ++i)
        #pragma unroll
        for (int j = 0; j < 4; ++j)
          acc[4 + i][j] = mfma16(af[i], bq[j], acc[4 + i][j]);
      __builtin_amdgcn_s_setprio(0);
      asm volatile("s_barrier" ::: "memory");
    }
  }

  // ---------------- epilogue ----------------
  #pragma unroll
  for (int ii = 0; ii < 8; ++ii) {
    const int row = m0 + wm*128 + ii*16 + quad*4;
    #pragma unroll
    for (int j = 0; j < 4; ++j) {
      const int col = n0 + wn*64 + j*16 + l16;
      if (VFUSE && col >= 2048) {
        const int b = row >> 11, tloc = row & 2047;
        const int h = (col - 2048) >> 6, d = col & 63;
        ushort4 pk;
        pk.x = f2b(acc[ii][j][0]);
        pk.y = f2b(acc[ii][j][1]);
        pk.z = f2b(acc[ii][j][2]);
        pk.w = f2b(acc[ii][j][3]);
        *(ushort4*)&vT[((size_t)((b*16 + h)*64 + d))*2048 + tloc] = pk;
      } else {
        float bv = BIAS ? bias[col] : 0.f;
        #pragma unroll
        for (int r = 0; r < 4; ++r) {
          float v = acc[ii][j][r] + bv;
          if (RELU) v = fmaxf(v, 0.f);
          ((unsigned short*)Cv)[(size_t)(row + r) * N + col] = f2b(v);
        }
      }
    }
  }
}

// ======= GEMM 128x128, 8-wave in-block K-split, BK=64, 3-buf counted vmcnt =======
__global__ __launch_bounds__(512)
void gemm_t128(const unsigned short* __restrict__ A, const unsigned short* __restrict__ Bt,
               const float* __restrict__ bias, const float* __restrict__ resid,
               float* __restrict__ C, int M, int N, int K) {
  __shared__ unsigned short SMEM[6*128*64];   // 96 KB: As[3] @0, Bs[3] @24576
  const int tid = threadIdx.x;
  const int lane = tid & 63;
  const int quad = lane >> 4, l16 = lane & 15;
  const int wave = tid >> 6;          // 0..7
  const int sub = wave >> 2;          // K-half of each BK=64 tile
  const int wq = wave & 3;
  const int wm = (wq >> 1) * 64, wn = (wq & 1) * 64;
  const int id = blockIdx.x;          // 256 blocks
  const int xcd = id & 7, i2 = id >> 3;
  const int mt = (xcd << 2) | (i2 >> 3);   // 0..31
  const int nt = i2 & 7;
  const int m0 = mt * 128, n0 = nt * 128;

  f32x4 acc[4][4];
  #pragma unroll
  for (int i = 0; i < 4; ++i)
    #pragma unroll
    for (int j = 0; j < 4; ++j) acc[i][j] = (f32x4){0.f, 0.f, 0.f, 0.f};

  const int srow = tid >> 3;                     // 0..63
  const int scc  = ((tid & 7) ^ (srow & 7)) * 8; // chunk-XOR pre-swizzled source
  const unsigned short* Ab = A + (size_t)m0 * K;
  const unsigned short* Bb = Bt + (size_t)n0 * K;

  auto stage = [&](int buf, int k0) {
    unsigned short* Ad = SMEM + buf * 8192;
    unsigned short* Bd = SMEM + 24576 + buf * 8192;
    gl2lds16(Ab + (size_t)srow * K + k0 + scc,        Ad + tid * 8);
    gl2lds16(Ab + (size_t)(srow + 64) * K + k0 + scc, Ad + 4096 + tid * 8);
    gl2lds16(Bb + (size_t)srow * K + k0 + scc,        Bd + tid * 8);
    gl2lds16(Bb + (size_t)(srow + 64) * K + k0 + scc, Bd + 4096 + tid * 8);
  };

  const int niter = K >> 6;   // 16 (proj) or 64 (FFN2)
  stage(0, 0);
  stage(1, 64);

  const int cc = sub * 4 + quad;   // this wave's k-chunk within the 64-col tile
  int bufc = 0;
  for (int it = 0; it < niter; ++it) {
    if (it + 1 < niter) {
      asm volatile("s_waitcnt vmcnt(4)" ::: "memory");
    } else {
      asm volatile("s_waitcnt vmcnt(0)" ::: "memory");
    }
    __builtin_amdgcn_s_barrier();
    if (it + 2 < niter) {
      int bufn = bufc + 2; if (bufn >= 3) bufn -= 3;
      stage(bufn, (it + 2) * 64);
    }
    const unsigned short* Ar = SMEM + bufc * 8192;
    const unsigned short* Br = SMEM + 24576 + bufc * 8192;
    bf16x8 af[4], bfr[4];
    #pragma unroll
    for (int i = 0; i < 4; ++i) {
      const int R = wm + i*16 + l16;
      af[i] = __builtin_bit_cast(bf16x8,
        *(const s16x8*)&Ar[R*64 + ((cc ^ (R & 7)) * 8)]);
    }
    #pragma unroll
    for (int j = 0; j < 4; ++j) {
      const int R = wn + j*16 + l16;
      bfr[j] = __builtin_bit_cast(bf16x8,
        *(const s16x8*)&Br[R*64 + ((cc ^ (R & 7)) * 8)]);
    }
    #pragma unroll
    for (int i = 0; i < 4; ++i)
      #pragma unroll
      for (int j = 0; j < 4; ++j)
        acc[i][j] = mfma16(af[i], bfr[j], acc[i][j]);
    bufc = (bufc == 2) ? 0 : bufc + 1;
  }

  // ---- combine K-halves through LDS (sub=1 dumps, sub=0 finishes) ----
  __syncthreads();
  float* ex = (float*)&SMEM[0];     // 64 KB used of 96
  float* w = ex + wq * 4096;
  if (sub == 1) {
    #pragma unroll
    for (int i = 0; i < 4; ++i)
      #pragma unroll
      for (int j = 0; j < 4; ++j)
        *(f32x4*)&w[(i*4 + j)*256 + lane*4] = acc[i][j];
  }
  __syncthreads();
  if (sub == 1) return;

  #pragma unroll
  for (int i = 0; i < 4; ++i) {
    const int row = m0 + wm + i*16 + quad*4;
    #pragma unroll
    for (int j = 0; j < 4; ++j) {
      f32x4 oth = *(const f32x4*)&w[(i*4 + j)*256 + lane*4];
      const int col = n0 + wn + j*16 + l16;
      const float bv = bias[col];
      #pragma unroll
      for (int r = 0; r < 4; ++r)
        C[(size_t)(row + r) * N + col] =
            acc[i][j][r] + oth[r] + bv + resid[(size_t)(row + r) * N + col];
    }
  }
}

// ---------------- causal flash attention: paired q-tiles, 4-buf K/V ring ----------------
// grid = 512: xcd = id&7, bh = xcd*4 + ((id>>3)&3) (4 bh per XCD -> 2MB K/V in L2),
// jA = id>>5 (0..15), jB = 31-jA (balanced pairs, 34 tile-units/block).
// SWAPPED QK^T (S^T = mfma(K,Q)): reg r ↔ kv, lane l16 ↔ q-row -> packed b64 P stores.
// 4-buffer K/V ring, stage 2 tiles at top of even its, ONE __syncthreads per 2 kv-tiles:
// halves barrier count and gives the scheduler 2 tile-computes (4 t-chains) per sync
// window. Staged loads overwrite buffers last read 2 tiles ago (pre-barrier) and have
// ~2 tile-computes of flight before the publishing barrier drains vmcnt.
__global__ __launch_bounds__(256)
void attn_kernel(const unsigned short* __restrict__ qkv,
                 const unsigned short* __restrict__ vT,
                 unsigned short* __restrict__ outc) {
  __shared__ unsigned short Ks[4][64*64];   // [kv][d], chunk-XOR swizzled, 32 KB
  __shared__ unsigned short Vs[4][64*64];   // [d][kv], chunk-XOR swizzled, 32 KB
  __shared__ unsigned short Ps[4*16*72];    // per-wave P [16 qrow][64+pad kv], 9 KB
  const int tid = threadIdx.x, lane = tid & 63, wave = tid >> 6;
  const int quad = lane >> 4, l16 = lane & 15;
  const int id = blockIdx.x;                 // 0..511
  const int xcd = id & 7;
  const int bh = xcd * 4 + ((id >> 3) & 3);  // same-XCD blocks share 4 bh values
  const int jA = id >> 5, jB = 31 - jA;      // paired q-tiles
  const int b = bh >> 4, h = bh & 15;
  const size_t tokbase = (size_t)b * 2048 * 3072;
  const unsigned short* Q  = qkv + tokbase + h * 64;
  const unsigned short* Kg = qkv + tokbase + 1024 + h * 64;
  const unsigned short* Vg = vT + (size_t)bh * 64 * 2048;

  const s16x8 ones_s = {0x3F80, 0x3F80, 0x3F80, 0x3F80, 0x3F80, 0x3F80, 0x3F80, 0x3F80};
  const bf16x8 onesf = __builtin_bit_cast(bf16x8, ones_s);

  // Q fragments, pre-scaled by (1/32)*log2(e) so S is already in exp2 domain
  bf16x8 qf[2][2];
  #pragma unroll
  for (int t = 0; t < 2; ++t) {
    const int qrow = (t ? jB : jA) * 64 + wave * 16 + l16;
    #pragma unroll
    for (int s = 0; s < 2; ++s) {
      s16x8 raw = *(const s16x8*)(Q + (size_t)qrow * 3072 + s * 32 + quad * 8);
      unsigned short* rp = (unsigned short*)&raw;
      #pragma unroll
      for (int k = 0; k < 8; ++k) rp[k] = f2b(b2f(rp[k]) * 0.0450842305f);
      qf[t][s] = __builtin_bit_cast(bf16x8, raw);
    }
  }

  f32x4 accO[2][4];
  f32x4 accS[2] = {(f32x4){0.f,0.f,0.f,0.f}, (f32x4){0.f,0.f,0.f,0.f}};
  #pragma unroll
  for (int t = 0; t < 2; ++t)
    #pragma unroll
    for (int i = 0; i < 4; ++i) accO[t][i] = (f32x4){0.f, 0.f, 0.f, 0.f};

  const int r8 = lane >> 3;
  const int cs = (((lane & 7) ^ r8) * 8);

  auto stage = [&](int buf, int kv0) {
    #pragma unroll
    for (int i = 0; i < 2; ++i) {
      int row = wave * 16 + i * 8;
      gl2lds16(Kg + (size_t)(kv0 + row + r8) * 3072 + cs, &Ks[buf][row * 64 + lane * 8]);
      gl2lds16(Vg + (size_t)(row + r8) * 2048 + kv0 + cs, &Vs[buf][row * 64 + lane * 8]);
    }
  };

  const int ntile = jB + 1;                  // >= 17
  stage(0, 0);
  stage(1, 64);
  __syncthreads();

  for (int it = 0; it < ntile; ++it) {
    const int buf = it & 3;
    if (!(it & 1)) {
      // top of each pair: prefetch the NEXT pair into the buffers read 2 tiles ago
      if (it + 2 < ntile) stage((it + 2) & 3, (it + 2) * 64);
      if (it + 3 < ntile) stage((it + 3) & 3, (it + 3) * 64);
    }

    #pragma unroll
    for (int t = 0; t < 2; ++t) {
      const int jT = t ? jB : jA;
      if (it > jT) continue;
      // ---- S^T = mfma(K, Q): reg r = kv offset, lane l16 = q-row ----
      f32x4 sv[4];
      #pragma unroll
      for (int ni = 0; ni < 4; ++ni) {
        sv[ni] = (f32x4){0.f, 0.f, 0.f, 0.f};
        #pragma unroll
        for (int s = 0; s < 2; ++s) {
          bf16x8 kf = __builtin_bit_cast(bf16x8,
            *(const s16x8*)&Ks[buf][(ni*16 + l16)*64 + (((s*4 + quad) ^ (l16 & 7)) * 8)]);
          sv[ni] = mfma16(kf, qf[t][s], sv[ni]);
        }
      }
      if (it == jT) {
        const int qr = jT*64 + wave*16 + l16;
        const int kvb = it*64 + quad*4;
        #pragma unroll
        for (int ni = 0; ni < 4; ++ni) {
          #pragma unroll
          for (int r = 0; r < 4; ++r)
            if (kvb + ni*16 + r > qr) sv[ni][r] = -__builtin_inff();
        }
      }
      // p = exp2(s); 4 consecutive kv at one q-row -> packed b64 store
      #pragma unroll
      for (int ni = 0; ni < 4; ++ni) {
        float p0 = exp2f(sv[ni][0]);
        float p1 = exp2f(sv[ni][1]);
        float p2 = exp2f(sv[ni][2]);
        float p3 = exp2f(sv[ni][3]);
        uint2 pk2;
        pk2.x = f2b2(p0, p1);
        pk2.y = f2b2(p2, p3);
        *(uint2*)&Ps[wave*1152 + l16*72 + ni*16 + quad*4] = pk2;
      }
      __asm__ volatile("s_waitcnt lgkmcnt(0)" ::: "memory");
      #pragma unroll
      for (int s = 0; s < 2; ++s) {
        bf16x8 pf = __builtin_bit_cast(bf16x8,
          *(const s16x8*)&Ps[wave*1152 + l16*72 + s*32 + quad*8]);
        accS[t] = mfma16(pf, onesf, accS[t]);   // row sums via ones-column MFMA
        #pragma unroll
        for (int ni = 0; ni < 4; ++ni) {
          bf16x8 vf = __builtin_bit_cast(bf16x8,
            *(const s16x8*)&Vs[buf][(ni*16 + l16)*64 + (((s*4 + quad) ^ (l16 & 7)) * 8)]);
          accO[t][ni] = mfma16(pf, vf, accO[t][ni]);
        }
      }
    }
    if (it & 1) __syncthreads();   // one barrier per 2 kv-tiles
  }

  #pragma unroll
  for (int t = 0; t < 2; ++t) {
    const int rowg = (t ? jB : jA)*64 + wave*16 + quad*4;
    float inv[4];
    #pragma unroll
    for (int r = 0; r < 4; ++r) inv[r] = __builtin_amdgcn_rcpf(accS[t][r]);
    #pragma unroll
    for (int ni = 0; ni < 4; ++ni)
      #pragma unroll
      for (int r = 0; r < 4; ++r)
        outc[(size_t)(b*2048 + rowg + r) * 1024 + h*64 + ni*16 + l16]
          = f2b(accO[t][ni][r] * inv[r]);
  }
}

extern "C" void kernel_launch(void* const* d_in, const int* in_sizes, int n_in,
                              void* d_out, int out_size, void* d_ws, size_t ws_size,
                              hipStream_t stream) {
  (void)in_sizes; (void)n_in; (void)out_size; (void)ws_size;
  const float* x   = (const float*)d_in[0];
  const float* wq  = (const float*)d_in[1];
  const float* wk  = (const float*)d_in[2];
  const float* wv  = (const float*)d_in[3];
  const float* wo  = (const float*)d_in[4];
  const float* bo  = (const float*)d_in[5];
  const float* g1  = (const float*)d_in[6];
  const float* b1  = (const float*)d_in[7];
  const float* g2  = (const float*)d_in[8];
  const float* b2  = (const float*)d_in[9];
  const float* w1  = (const float*)d_in[10];
  const float* bf1 = (const float*)d_in[11];
  const float* w2  = (const float*)d_in[12];
  const float* bf2 = (const float*)d_in[13];
  float* out = (float*)d_out;

  unsigned short* ws    = (unsigned short*)d_ws;
  unsigned short* wqkvt = ws;                        // bf16 [3072][1024]
  unsigned short* wot   = wqkvt + 3*1024*1024;       // bf16 [1024][1024]
  unsigned short* w1t   = wot   + 1024*1024;         // bf16 [4096][1024]
  unsigned short* w2t   = w1t   + 4096*1024;         // bf16 [1024][4096]
  unsigned short* hbuf  = w2t   + 4096*1024;         // bf16 [4096][1024] (LN1/LN2 out)
  unsigned short* qkvb  = hbuf  + 4096*1024;         // bf16 [4096][3072] (V region unused)
  unsigned short* attnb = qkvb  + (size_t)4096*3072; // bf16 [4096][1024]
  float*          x2b   = (float*)(attnb + 4096*1024); // f32 [4096][1024]
  unsigned short* vTb   = (unsigned short*)x2b;      // bf16 [32][64][2048] — dead before x2b written
  unsigned short* midb  = qkvb;                      // bf16 [4096][4096] overlaps qkvb+attnb (dead)

  dim3 tb(32, 8);
  transpose_qkv<<<dim3(2,32,48), tb, 0, stream>>>(wq, wk, wv, wqkvt);
  transpose_k<<<dim3(32,32,1),  tb, 0, stream>>>(wo, wot, 1024, 1024, 0, 0);
  transpose_k<<<dim3(128,32,1), tb, 0, stream>>>(w1, w1t, 1024, 4096, 0, 0);
  transpose_k<<<dim3(32,128,1), tb, 0, stream>>>(w2, w2t, 4096, 1024, 0, 0);

  ln_kernel<<<4096, 256, 0, stream>>>(x, g1, b1, hbuf);
  // QKV GEMM (256^2 8-phase) with fused V-transpose epilogue (V region -> vTb)
  gemm8p<false,false,true><<<192, 512, 0, stream>>>(
      hbuf, wqkvt, nullptr, qkvb, vTb, 12, 3072, 1024);
  attn_kernel<<<512, 256, 0, stream>>>(qkvb, vTb, attnb);
  gemm_t128<<<256, 512, 0, stream>>>(attnb, wot, bo, x, x2b, 4096, 1024, 1024);
  ln_kernel<<<4096, 256, 0, stream>>>(x2b, g2, b2, hbuf);
  // FFN1 (256^2 8-phase): relu + bias, bf16 out
  gemm8p<true,true,false><<<256, 512, 0, stream>>>(
      hbuf, w1t, bf1, midb, nullptr, 16, 4096, 1024);
  gemm_t128<<<256, 512, 0, stream>>>(midb, w2t, bf2, x2b, out, 4096, 1024, 4096);
}

// Round 8
// 318.513 us; speedup vs baseline: 1.0293x; 1.0293x over previous
//
#include <hip/hip_runtime.h>
#include <hip/hip_bf16.h>

typedef __bf16 bf16x8 __attribute__((ext_vector_type(8)));
typedef float f32x4 __attribute__((ext_vector_type(4)));
typedef short s16x8 __attribute__((ext_vector_type(8)));

#define DEV __device__ __forceinline__

DEV float b2f(unsigned short u) {
  unsigned int x = ((unsigned int)u) << 16;
  return __builtin_bit_cast(float, x);
}
DEV unsigned short f2b(float f) {
  unsigned int x = __builtin_bit_cast(unsigned int, f);
  x += 0x7fffu + ((x >> 16) & 1u);
  return (unsigned short)(x >> 16);
}
DEV unsigned int f2b2(float a, float b) {
  float2 t; t.x = a; t.y = b;
  __hip_bfloat162 v = __float22bfloat162_rn(t);
  unsigned int r;
  __builtin_memcpy(&r, &v, 4);
  return r;
}
DEV f32x4 mfma16(bf16x8 a, bf16x8 b, f32x4 c) {
  return __builtin_amdgcn_mfma_f32_16x16x32_bf16(a, b, c, 0, 0, 0);
}
DEV void gl2lds16(const unsigned short* g, unsigned short* l) {
  __builtin_amdgcn_global_load_lds(
      (const __attribute__((address_space(1))) void*)g,
      (__attribute__((address_space(3))) void*)l, 16, 0, 0);
}

// ------- tiled transpose + f32->bf16 convert: in[K][N] f32 (+z) -> out[N][K] bf16 -------
__global__ __launch_bounds__(256)
void transpose_k(const float* __restrict__ in, unsigned short* __restrict__ out,
                 int K, int N, long zin, long zout) {
  __shared__ float tile[32][33];
  in  += (size_t)blockIdx.z * zin;
  out += (size_t)blockIdx.z * zout;
  int n0 = blockIdx.x * 32, k0 = blockIdx.y * 32;
  int tx = threadIdx.x, ty = threadIdx.y;
  #pragma unroll
  for (int i = ty; i < 32; i += 8)
    tile[i][tx] = in[(size_t)(k0 + i) * N + n0 + tx];
  __syncthreads();
  #pragma unroll
  for (int i = ty; i < 32; i += 8)
    out[(size_t)(n0 + i) * K + k0 + tx] = f2b(tile[tx][i]);
}

// ------- fused QKV weight transpose: wq/wk/wv [16][1024][64] f32 -> [3072][1024] bf16 ----
__global__ __launch_bounds__(256)
void transpose_qkv(const float* __restrict__ wq, const float* __restrict__ wk,
                   const float* __restrict__ wv, unsigned short* __restrict__ out) {
  __shared__ float tile[32][33];
  const int z = blockIdx.z;   // 0..47
  const float* in = (z < 16) ? (wq + (size_t)z * 65536)
                  : (z < 32) ? (wk + (size_t)(z - 16) * 65536)
                             : (wv + (size_t)(z - 32) * 65536);
  unsigned short* o = out + (size_t)z * 65536;
  int n0 = blockIdx.x * 32, k0 = blockIdx.y * 32;   // N=64, K=1024
  int tx = threadIdx.x, ty = threadIdx.y;
  #pragma unroll
  for (int i = ty; i < 32; i += 8)
    tile[i][tx] = in[(size_t)(k0 + i) * 64 + n0 + tx];
  __syncthreads();
  #pragma unroll
  for (int i = ty; i < 32; i += 8)
    o[(size_t)(n0 + i) * 1024 + k0 + tx] = f2b(tile[tx][i]);
}

// ---------------- LayerNorm over rows of 1024: f32 in -> bf16 out ----------------
__global__ __launch_bounds__(256)
void ln_kernel(const float* __restrict__ x, const float* __restrict__ g,
               const float* __restrict__ b, unsigned short* __restrict__ o) {
  __shared__ float rs[4];
  __shared__ float rq[4];
  int row = blockIdx.x, tid = threadIdx.x;
  const float* xr = x + (size_t)row * 1024;
  float4 raw = ((const float4*)xr)[tid];
  float s = raw.x + raw.y + raw.z + raw.w;
  float q = raw.x*raw.x + raw.y*raw.y + raw.z*raw.z + raw.w*raw.w;
  #pragma unroll
  for (int off = 32; off > 0; off >>= 1) {
    s += __shfl_down(s, off);
    q += __shfl_down(q, off);
  }
  int wave = tid >> 6;
  if ((tid & 63) == 0) { rs[wave] = s; rq[wave] = q; }
  __syncthreads();
  float ts = rs[0] + rs[1] + rs[2] + rs[3];
  float tq = rq[0] + rq[1] + rq[2] + rq[3];
  float mean = ts * (1.0f/1024.0f);
  float var = tq * (1.0f/1024.0f) - mean*mean;
  float rstd = rsqrtf(var + 1e-5f);
  float4 gr = ((const float4*)g)[tid];
  float4 br = ((const float4*)b)[tid];
  float o0 = (raw.x-mean)*rstd*gr.x + br.x;
  float o1 = (raw.y-mean)*rstd*gr.y + br.y;
  float o2 = (raw.z-mean)*rstd*gr.z + br.z;
  float o3 = (raw.w-mean)*rstd*gr.w + br.w;
  uint2 ov;
  ov.x = f2b2(o0, o1);
  ov.y = f2b2(o2, o3);
  ((uint2*)(o + (size_t)row * 1024))[tid] = ov;
}

// ======== GEMM 256x256, BK=32, 8 waves, 4-deep LDS ring, counted vmcnt + setprio ========
template<bool RELU, bool BIAS, bool VFUSE>
__global__ __launch_bounds__(512, 2)
void gemm8p(const unsigned short* __restrict__ A, const unsigned short* __restrict__ Bt,
            const float* __restrict__ bias, void* __restrict__ Cv,
            unsigned short* __restrict__ vT, int NTn, int N, int K) {
  __shared__ unsigned short As[4][256*32];   // 4 x 16 KB
  __shared__ unsigned short Bs[4][256*32];   // 4 x 16 KB  (128 KB total)
  const int tid = threadIdx.x;
  const int lane = tid & 63, wave = tid >> 6;
  const int quad = lane >> 4, l16 = lane & 15;
  const int wm = wave >> 2, wn = wave & 3;       // 2 x 4 wave grid
  const int nwg = gridDim.x;
  const int id = blockIdx.x;
  const int id2 = (id & 7) * (nwg >> 3) + (id >> 3);  // XCD-chunked (nwg % 8 == 0)
  const int mt = id2 / NTn, nt = id2 % NTn;
  const int m0 = mt * 256, n0 = nt * 256;

  f32x4 acc[8][4];
  #pragma unroll
  for (int i = 0; i < 8; ++i)
    #pragma unroll
    for (int j = 0; j < 4; ++j) acc[i][j] = (f32x4){0.f, 0.f, 0.f, 0.f};

  const int srow = tid >> 2;                               // 0..127
  const int scc  = (((tid & 3) ^ ((srow >> 1) & 3)) * 8);  // pre-swizzled source chunk
  const unsigned short* Ab = A + (size_t)m0 * K;
  const unsigned short* Bb = Bt + (size_t)n0 * K;

  const int NT = K >> 5;         // K-tiles (K=1024 -> 32)
  const int H  = NT << 2;        // half-tile stream length

  auto stage = [&](int h) {
    const int Tt = h >> 2, part = h & 3, kk = Tt << 5;
    const int buf = Tt & 3;
    if (part == 0)
      gl2lds16(Ab + (size_t)srow * K + kk + scc,         &As[buf][tid * 8]);
    else if (part == 1)
      gl2lds16(Ab + (size_t)(srow + 128) * K + kk + scc, &As[buf][4096 + tid * 8]);
    else if (part == 2)
      gl2lds16(Bb + (size_t)srow * K + kk + scc,         &Bs[buf][tid * 8]);
    else
      gl2lds16(Bb + (size_t)(srow + 128) * K + kk + scc, &Bs[buf][4096 + tid * 8]);
  };

  // prologue: tiles 0,1 fully + tile 2's A halves in flight
  #pragma unroll
  for (int h = 0; h < 10; ++h) stage(h);
  asm volatile("s_waitcnt vmcnt(6)" ::: "memory");   // tile 0 resident
  asm volatile("s_barrier" ::: "memory");

  const int qsw = (quad ^ ((l16 >> 1) & 3)) * 8;   // lane-constant read swizzle
  const int arow0 = wm * 128 + l16;
  const int brow0 = wn * 64 + l16;

  for (int T = 0; T < NT; ++T) {
    const int buf = T & 3;
    bf16x8 bq[4];
    // ---------- phase 1 (rows 0..63 of wave tile) ----------
    {
      bf16x8 af[4];
      #pragma unroll
      for (int i = 0; i < 4; ++i)
        af[i] = __builtin_bit_cast(bf16x8,
          *(const s16x8*)&As[buf][(arow0 + i*16)*32 + qsw]);
      #pragma unroll
      for (int j = 0; j < 4; ++j)
        bq[j] = __builtin_bit_cast(bf16x8,
          *(const s16x8*)&Bs[buf][(brow0 + j*16)*32 + qsw]);
      const int h = 4*T + 10;
      if (h < H)     stage(h);
      if (h + 1 < H) stage(h + 1);
      asm volatile("s_barrier" ::: "memory");
      __builtin_amdgcn_s_setprio(1);
      #pragma unroll
      for (int i = 0; i < 4; ++i)
        #pragma unroll
        for (int j = 0; j < 4; ++j)
          acc[i][j] = mfma16(af[i], bq[j], acc[i][j]);
      __builtin_amdgcn_s_setprio(0);
      asm volatile("s_barrier" ::: "memory");
    }
    // ---------- phase 2 (rows 64..127 of wave tile) ----------
    {
      bf16x8 af[4];
      #pragma unroll
      for (int i = 0; i < 4; ++i)
        af[i] = __builtin_bit_cast(bf16x8,
          *(const s16x8*)&As[buf][(arow0 + 64 + i*16)*32 + qsw]);
      const int h = 4*T + 12;
      if (h < H)     stage(h);
      if (h + 1 < H) stage(h + 1);
      if (T + 3 < NT)      { asm volatile("s_waitcnt vmcnt(6)" ::: "memory"); }
      else if (T + 2 < NT) { asm volatile("s_waitcnt vmcnt(4)" ::: "memory"); }
      else if (T + 1 < NT) { asm volatile("s_waitcnt vmcnt(0)" ::: "memory"); }
      asm volatile("s_barrier" ::: "memory");
      __builtin_amdgcn_s_setprio(1);
      #pragma unroll
      for (int i = 0; i < 4; ++i)
        #pragma unroll
        for (int j = 0; j < 4; ++j)
          acc[4 + i][j] = mfma16(af[i], bq[j], acc[4 + i][j]);
      __builtin_amdgcn_s_setprio(0);
      asm volatile("s_barrier" ::: "memory");
    }
  }

  // ---------------- epilogue ----------------
  #pragma unroll
  for (int ii = 0; ii < 8; ++ii) {
    const int row = m0 + wm*128 + ii*16 + quad*4;
    #pragma unroll
    for (int j = 0; j < 4; ++j) {
      const int col = n0 + wn*64 + j*16 + l16;
      if (VFUSE && col >= 2048) {
        const int b = row >> 11, tloc = row & 2047;
        const int h = (col - 2048) >> 6, d = col & 63;
        ushort4 pk;
        pk.x = f2b(acc[ii][j][0]);
        pk.y = f2b(acc[ii][j][1]);
        pk.z = f2b(acc[ii][j][2]);
        pk.w = f2b(acc[ii][j][3]);
        *(ushort4*)&vT[((size_t)((b*16 + h)*64 + d))*2048 + tloc] = pk;
      } else {
        float bv = BIAS ? bias[col] : 0.f;
        #pragma unroll
        for (int r = 0; r < 4; ++r) {
          float v = acc[ii][j][r] + bv;
          if (RELU) v = fmaxf(v, 0.f);
          ((unsigned short*)Cv)[(size_t)(row + r) * N + col] = f2b(v);
        }
      }
    }
  }
}

// ======= GEMM 128x128, 8-wave in-block K-split, BK=64, 3-buf counted vmcnt =======
__global__ __launch_bounds__(512)
void gemm_t128(const unsigned short* __restrict__ A, const unsigned short* __restrict__ Bt,
               const float* __restrict__ bias, const float* __restrict__ resid,
               float* __restrict__ C, int M, int N, int K) {
  __shared__ unsigned short SMEM[6*128*64];   // 96 KB: As[3] @0, Bs[3] @24576
  const int tid = threadIdx.x;
  const int lane = tid & 63;
  const int quad = lane >> 4, l16 = lane & 15;
  const int wave = tid >> 6;          // 0..7
  const int sub = wave >> 2;          // K-half of each BK=64 tile
  const int wq = wave & 3;
  const int wm = (wq >> 1) * 64, wn = (wq & 1) * 64;
  const int id = blockIdx.x;          // 256 blocks
  const int xcd = id & 7, i2 = id >> 3;
  const int mt = (xcd << 2) | (i2 >> 3);   // 0..31
  const int nt = i2 & 7;
  const int m0 = mt * 128, n0 = nt * 128;

  f32x4 acc[4][4];
  #pragma unroll
  for (int i = 0; i < 4; ++i)
    #pragma unroll
    for (int j = 0; j < 4; ++j) acc[i][j] = (f32x4){0.f, 0.f, 0.f, 0.f};

  const int srow = tid >> 3;                     // 0..63
  const int scc  = ((tid & 7) ^ (srow & 7)) * 8; // chunk-XOR pre-swizzled source
  const unsigned short* Ab = A + (size_t)m0 * K;
  const unsigned short* Bb = Bt + (size_t)n0 * K;

  auto stage = [&](int buf, int k0) {
    unsigned short* Ad = SMEM + buf * 8192;
    unsigned short* Bd = SMEM + 24576 + buf * 8192;
    gl2lds16(Ab + (size_t)srow * K + k0 + scc,        Ad + tid * 8);
    gl2lds16(Ab + (size_t)(srow + 64) * K + k0 + scc, Ad + 4096 + tid * 8);
    gl2lds16(Bb + (size_t)srow * K + k0 + scc,        Bd + tid * 8);
    gl2lds16(Bb + (size_t)(srow + 64) * K + k0 + scc, Bd + 4096 + tid * 8);
  };

  const int niter = K >> 6;   // 16 (proj) or 64 (FFN2)
  stage(0, 0);
  stage(1, 64);

  const int cc = sub * 4 + quad;   // this wave's k-chunk within the 64-col tile
  int bufc = 0;
  for (int it = 0; it < niter; ++it) {
    if (it + 1 < niter) {
      asm volatile("s_waitcnt vmcnt(4)" ::: "memory");
    } else {
      asm volatile("s_waitcnt vmcnt(0)" ::: "memory");
    }
    __builtin_amdgcn_s_barrier();
    if (it + 2 < niter) {
      int bufn = bufc + 2; if (bufn >= 3) bufn -= 3;
      stage(bufn, (it + 2) * 64);
    }
    const unsigned short* Ar = SMEM + bufc * 8192;
    const unsigned short* Br = SMEM + 24576 + bufc * 8192;
    bf16x8 af[4], bfr[4];
    #pragma unroll
    for (int i = 0; i < 4; ++i) {
      const int R = wm + i*16 + l16;
      af[i] = __builtin_bit_cast(bf16x8,
        *(const s16x8*)&Ar[R*64 + ((cc ^ (R & 7)) * 8)]);
    }
    #pragma unroll
    for (int j = 0; j < 4; ++j) {
      const int R = wn + j*16 + l16;
      bfr[j] = __builtin_bit_cast(bf16x8,
        *(const s16x8*)&Br[R*64 + ((cc ^ (R & 7)) * 8)]);
    }
    #pragma unroll
    for (int i = 0; i < 4; ++i)
      #pragma unroll
      for (int j = 0; j < 4; ++j)
        acc[i][j] = mfma16(af[i], bfr[j], acc[i][j]);
    bufc = (bufc == 2) ? 0 : bufc + 1;
  }

  // ---- combine K-halves through LDS (sub=1 dumps, sub=0 finishes) ----
  __syncthreads();
  float* ex = (float*)&SMEM[0];     // 64 KB used of 96
  float* w = ex + wq * 4096;
  if (sub == 1) {
    #pragma unroll
    for (int i = 0; i < 4; ++i)
      #pragma unroll
      for (int j = 0; j < 4; ++j)
        *(f32x4*)&w[(i*4 + j)*256 + lane*4] = acc[i][j];
  }
  __syncthreads();
  if (sub == 1) return;

  #pragma unroll
  for (int i = 0; i < 4; ++i) {
    const int row = m0 + wm + i*16 + quad*4;
    #pragma unroll
    for (int j = 0; j < 4; ++j) {
      f32x4 oth = *(const f32x4*)&w[(i*4 + j)*256 + lane*4];
      const int col = n0 + wn + j*16 + l16;
      const float bv = bias[col];
      #pragma unroll
      for (int r = 0; r < 4; ++r)
        C[(size_t)(row + r) * N + col] =
            acc[i][j][r] + oth[r] + bv + resid[(size_t)(row + r) * N + col];
    }
  }
}

// ---------------- causal flash attention: paired q-tiles, split-phase softmax ----------------
// grid = 512: xcd = id&7, bh = xcd*4 + ((id>>3)&3) (4 bh per XCD -> 2MB K/V in L2),
// jA = id>>5 (0..15), jB = 31-jA (balanced pairs, 34 tile-units/block).
// SWAPPED QK^T (S^T = mfma(K,Q)): reg r ↔ kv, lane l16 ↔ q-row -> packed b64 P stores.
// KEY (R8): Ps is per-t (Ps[2][..]) and each tile runs phase A = {QK+exp+store for BOTH
// t-chains} -> ONE lgkmcnt(0) -> phase B = {rowsum+PV for both}. Previously both t shared
// one Ps region with a full LDS drain per t, hard-serializing the two chains.
// Ps uses the same chunk-XOR layout as Ks (proven 0-conflict on b128 reads).
__global__ __launch_bounds__(256)
void attn_kernel(const unsigned short* __restrict__ qkv,
                 const unsigned short* __restrict__ vT,
                 unsigned short* __restrict__ outc) {
  __shared__ unsigned short Ks[2][64*64];     // [kv][d], chunk-XOR swizzled, 16 KB
  __shared__ unsigned short Vs[2][64*64];     // [d][kv], chunk-XOR swizzled, 16 KB
  __shared__ unsigned short Ps[2][4*16*64];   // [t][wave*16+q][kv], chunk-XOR, 16 KB
  const int tid = threadIdx.x, lane = tid & 63, wave = tid >> 6;
  const int quad = lane >> 4, l16 = lane & 15;
  const int id = blockIdx.x;                 // 0..511
  const int xcd = id & 7;
  const int bh = xcd * 4 + ((id >> 3) & 3);  // same-XCD blocks share 4 bh values
  const int jA = id >> 5, jB = 31 - jA;      // paired q-tiles
  const int b = bh >> 4, h = bh & 15;
  const size_t tokbase = (size_t)b * 2048 * 3072;
  const unsigned short* Q  = qkv + tokbase + h * 64;
  const unsigned short* Kg = qkv + tokbase + 1024 + h * 64;
  const unsigned short* Vg = vT + (size_t)bh * 64 * 2048;

  const s16x8 ones_s = {0x3F80, 0x3F80, 0x3F80, 0x3F80, 0x3F80, 0x3F80, 0x3F80, 0x3F80};
  const bf16x8 onesf = __builtin_bit_cast(bf16x8, ones_s);

  // Q fragments, pre-scaled by (1/32)*log2(e) so S is already in exp2 domain
  bf16x8 qf[2][2];
  #pragma unroll
  for (int t = 0; t < 2; ++t) {
    const int qrow = (t ? jB : jA) * 64 + wave * 16 + l16;
    #pragma unroll
    for (int s = 0; s < 2; ++s) {
      s16x8 raw = *(const s16x8*)(Q + (size_t)qrow * 3072 + s * 32 + quad * 8);
      unsigned short* rp = (unsigned short*)&raw;
      #pragma unroll
      for (int k = 0; k < 8; ++k) rp[k] = f2b(b2f(rp[k]) * 0.0450842305f);
      qf[t][s] = __builtin_bit_cast(bf16x8, raw);
    }
  }

  f32x4 accO[2][4];
  f32x4 accS[2] = {(f32x4){0.f,0.f,0.f,0.f}, (f32x4){0.f,0.f,0.f,0.f}};
  #pragma unroll
  for (int t = 0; t < 2; ++t)
    #pragma unroll
    for (int i = 0; i < 4; ++i) accO[t][i] = (f32x4){0.f, 0.f, 0.f, 0.f};

  const int r8 = lane >> 3;
  const int cs = (((lane & 7) ^ r8) * 8);

  auto stage = [&](int buf, int kv0) {
    #pragma unroll
    for (int i = 0; i < 2; ++i) {
      int row = wave * 16 + i * 8;
      gl2lds16(Kg + (size_t)(kv0 + row + r8) * 3072 + cs, &Ks[buf][row * 64 + lane * 8]);
      gl2lds16(Vg + (size_t)(row + r8) * 2048 + kv0 + cs, &Vs[buf][row * 64 + lane * 8]);
    }
  };

  // per-lane Ps addressing (chunk-XOR, same involution as Ks/Vs)
  const int prow = (wave*16 + l16) * 64;                 // q-row base (shorts)
  const int pq7  = l16 & 7;

  const int ntile = jB + 1;
  stage(0, 0);
  __syncthreads();

  for (int it = 0; it < ntile; ++it) {
    const int buf = it & 1;
    if (it + 1 < ntile) stage(buf ^ 1, (it + 1) * 64);
    const bool act0 = (it <= jA);

    // ================= phase A: QK^T + exp2 + pack for both t-chains =================
    #pragma unroll
    for (int t = 0; t < 2; ++t) {
      if (t == 0 && !act0) continue;
      const int jT = t ? jB : jA;
      f32x4 sv[4];
      #pragma unroll
      for (int ni = 0; ni < 4; ++ni) {
        sv[ni] = (f32x4){0.f, 0.f, 0.f, 0.f};
        #pragma unroll
        for (int s = 0; s < 2; ++s) {
          bf16x8 kf = __builtin_bit_cast(bf16x8,
            *(const s16x8*)&Ks[buf][(ni*16 + l16)*64 + (((s*4 + quad) ^ (l16 & 7)) * 8)]);
          sv[ni] = mfma16(kf, qf[t][s], sv[ni]);
        }
      }
      if (it == jT) {
        const int qr = jT*64 + wave*16 + l16;
        const int kvb = it*64 + quad*4;
        #pragma unroll
        for (int ni = 0; ni < 4; ++ni) {
          #pragma unroll
          for (int r = 0; r < 4; ++r)
            if (kvb + ni*16 + r > qr) sv[ni][r] = -__builtin_inff();
        }
      }
      #pragma unroll
      for (int ni = 0; ni < 4; ++ni) {
        float p0 = exp2f(sv[ni][0]);
        float p1 = exp2f(sv[ni][1]);
        float p2 = exp2f(sv[ni][2]);
        float p3 = exp2f(sv[ni][3]);
        uint2 pk2;
        pk2.x = f2b2(p0, p1);
        pk2.y = f2b2(p2, p3);
        // kv = ni*16 + quad*4 -> chunk 2ni+(quad>>1), within-chunk (quad&1)*4, XOR q&7
        const int pc = ((2*ni + (quad >> 1)) ^ pq7) * 8 + (quad & 1) * 4;
        *(uint2*)&Ps[t][prow + pc] = pk2;
      }
    }
    __asm__ volatile("s_waitcnt lgkmcnt(0)" ::: "memory");

    // ================= phase B: row-sum + PV for both t-chains =================
    #pragma unroll
    for (int t = 0; t < 2; ++t) {
      if (t == 0 && !act0) continue;
      #pragma unroll
      for (int s = 0; s < 2; ++s) {
        bf16x8 pf = __builtin_bit_cast(bf16x8,
          *(const s16x8*)&Ps[t][prow + (((s*4 + quad) ^ pq7) * 8)]);
        accS[t] = mfma16(pf, onesf, accS[t]);   // row sums via ones-column MFMA
        #pragma unroll
        for (int ni = 0; ni < 4; ++ni) {
          bf16x8 vf = __builtin_bit_cast(bf16x8,
            *(const s16x8*)&Vs[buf][(ni*16 + l16)*64 + (((s*4 + quad) ^ (l16 & 7)) * 8)]);
          accO[t][ni] = mfma16(pf, vf, accO[t][ni]);
        }
      }
    }
    __syncthreads();
  }

  #pragma unroll
  for (int t = 0; t < 2; ++t) {
    const int rowg = (t ? jB : jA)*64 + wave*16 + quad*4;
    float inv[4];
    #pragma unroll
    for (int r = 0; r < 4; ++r) inv[r] = __builtin_amdgcn_rcpf(accS[t][r]);
    #pragma unroll
    for (int ni = 0; ni < 4; ++ni)
      #pragma unroll
      for (int r = 0; r < 4; ++r)
        outc[(size_t)(b*2048 + rowg + r) * 1024 + h*64 + ni*16 + l16]
          = f2b(accO[t][ni][r] * inv[r]);
  }
}

extern "C" void kernel_launch(void* const* d_in, const int* in_sizes, int n_in,
                              void* d_out, int out_size, void* d_ws, size_t ws_size,
                              hipStream_t stream) {
  (void)in_sizes; (void)n_in; (void)out_size; (void)ws_size;
  const float* x   = (const float*)d_in[0];
  const float* wq  = (const float*)d_in[1];
  const float* wk  = (const float*)d_in[2];
  const float* wv  = (const float*)d_in[3];
  const float* wo  = (const float*)d_in[4];
  const float* bo  = (const float*)d_in[5];
  const float* g1  = (const float*)d_in[6];
  const float* b1  = (const float*)d_in[7];
  const float* g2  = (const float*)d_in[8];
  const float* b2  = (const float*)d_in[9];
  const float* w1  = (const float*)d_in[10];
  const float* bf1 = (const float*)d_in[11];
  const float* w2  = (const float*)d_in[12];
  const float* bf2 = (const float*)d_in[13];
  float* out = (float*)d_out;

  unsigned short* ws    = (unsigned short*)d_ws;
  unsigned short* wqkvt = ws;                        // bf16 [3072][1024]
  unsigned short* wot   = wqkvt + 3*1024*1024;       // bf16 [1024][1024]
  unsigned short* w1t   = wot   + 1024*1024;         // bf16 [4096][1024]
  unsigned short* w2t   = w1t   + 4096*1024;         // bf16 [1024][4096]
  unsigned short* hbuf  = w2t   + 4096*1024;         // bf16 [4096][1024] (LN1/LN2 out)
  unsigned short* qkvb  = hbuf  + 4096*1024;         // bf16 [4096][3072] (V region unused)
  unsigned short* attnb = qkvb  + (size_t)4096*3072; // bf16 [4096][1024]
  float*          x2b   = (float*)(attnb + 4096*1024); // f32 [4096][1024]
  unsigned short* vTb   = (unsigned short*)x2b;      // bf16 [32][64][2048] — dead before x2b written
  unsigned short* midb  = qkvb;                      // bf16 [4096][4096] overlaps qkvb+attnb (dead)

  dim3 tb(32, 8);
  transpose_qkv<<<dim3(2,32,48), tb, 0, stream>>>(wq, wk, wv, wqkvt);
  transpose_k<<<dim3(32,32,1),  tb, 0, stream>>>(wo, wot, 1024, 1024, 0, 0);
  transpose_k<<<dim3(128,32,1), tb, 0, stream>>>(w1, w1t, 1024, 4096, 0, 0);
  transpose_k<<<dim3(32,128,1), tb, 0, stream>>>(w2, w2t, 4096, 1024, 0, 0);

  ln_kernel<<<4096, 256, 0, stream>>>(x, g1, b1, hbuf);
  // QKV GEMM (256^2 8-phase) with fused V-transpose epilogue (V region -> vTb)
  gemm8p<false,false,true><<<192, 512, 0, stream>>>(
      hbuf, wqkvt, nullptr, qkvb, vTb, 12, 3072, 1024);
  attn_kernel<<<512, 256, 0, stream>>>(qkvb, vTb, attnb);
  gemm_t128<<<256, 512, 0, stream>>>(attnb, wot, bo, x, x2b, 4096, 1024, 1024);
  ln_kernel<<<4096, 256, 0, stream>>>(x2b, g2, b2, hbuf);
  // FFN1 (256^2 8-phase): relu + bias, bf16 out
  gemm8p<true,true,false><<<256, 512, 0, stream>>>(
      hbuf, w1t, bf1, midb, nullptr, 16, 4096, 1024);
  gemm_t128<<<256, 512, 0, stream>>>(midb, w2t, bf2, x2b, out, 4096, 1024, 4096);
}